// Round 7
// baseline (1724.738 us; speedup 1.0000x reference)
//
#include <hip/hip_runtime.h>
#include <hip/hip_cooperative_groups.h>
#include <hip/hip_bf16.h>
#include <math.h>

namespace cg = cooperative_groups;

constexpr int L = 4, D = 512, H = 8, DFF = 2048, T = 256, B = 8, BUCKETS = 32;
constexpr int DH = D / H;          // 64
constexpr int NT = B * T;          // 2048 rows
constexpr int QKVLD = 3 * D;       // 1536

typedef __attribute__((ext_vector_type(8))) short bf16x8;
typedef __attribute__((ext_vector_type(4))) float f32x4;

__device__ __forceinline__ unsigned short f2bf(float f) {
    unsigned int x = __float_as_uint(f);
    return (unsigned short)((x + 0x7fffu + ((x >> 16) & 1u)) >> 16);
}
__device__ __forceinline__ float bf2f(unsigned short u) {
    return __uint_as_float((unsigned int)u << 16);
}

__device__ __forceinline__ void stage16(const unsigned short* g, short* l) {
    __builtin_amdgcn_global_load_lds((const __attribute__((address_space(1))) unsigned int*)g,
                                     (__attribute__((address_space(3))) unsigned int*)l,
                                     16, 0, 0);
}

// ===========================================================================
// PART 1: standalone kernels (round-5, proven) — fallback path
// ===========================================================================

__global__ __launch_bounds__(256) void embed_kernel(const float* __restrict__ src,
                                                    float* __restrict__ x)
{
    int t = blockIdx.x, tid = threadIdx.x;
    float pe0, pe1;
    {
        int d0 = tid, d1 = tid + 256;
        float dv0 = expf(-(float)(2 * (d0 >> 1)) * (9.210340371976184f / (float)D));
        float dv1 = expf(-(float)(2 * (d1 >> 1)) * (9.210340371976184f / (float)D));
        float a0 = (float)t * dv0, a1 = (float)t * dv1;
        pe0 = (d0 & 1) ? cosf(a0) : sinf(a0);
        pe1 = (d1 & 1) ? cosf(a1) : sinf(a1);
    }
#pragma unroll
    for (int b = 0; b < B; b++) {
        const float* sp = src + ((size_t)t * B + b) * D;
        float* xp = x + ((size_t)(b * T + t)) * D;
        xp[tid]       = sp[tid]       * 22.62741699796952f + pe0;
        xp[tid + 256] = sp[tid + 256] * 22.62741699796952f + pe1;
    }
}

__device__ __forceinline__ void ln_vals_k(float v0, float v1,
                                          const float* __restrict__ g,
                                          const float* __restrict__ bb,
                                          float* o0, float* o1, int tid)
{
    float s = v0 + v1, q2 = v0 * v0 + v1 * v1;
#pragma unroll
    for (int o = 32; o; o >>= 1) { s += __shfl_xor(s, o); q2 += __shfl_xor(q2, o); }
    __shared__ float rs[4], rq[4];
    int lane = tid & 63, wid = tid >> 6;
    if (lane == 0) { rs[wid] = s; rq[wid] = q2; }
    __syncthreads();
    s = rs[0] + rs[1] + rs[2] + rs[3];
    q2 = rq[0] + rq[1] + rq[2] + rq[3];
    float mean = s * (1.f / (float)D);
    float var = q2 * (1.f / (float)D) - mean * mean;
    float rstd = rsqrtf(var + 1e-6f);
    *o0 = (v0 - mean) * rstd * g[tid] + bb[tid];
    *o1 = (v1 - mean) * rstd * g[tid + 256] + bb[tid + 256];
}

__global__ __launch_bounds__(256) void ln_kernel(const float* __restrict__ x,
                                                 unsigned short* __restrict__ y,
                                                 const float* __restrict__ g,
                                                 const float* __restrict__ bb)
{
    int row = blockIdx.x, tid = threadIdx.x;
    float v0 = x[(size_t)row * D + tid], v1 = x[(size_t)row * D + tid + 256];
    float o0, o1;
    ln_vals_k(v0, v1, g, bb, &o0, &o1, tid);
    y[(size_t)row * D + tid] = f2bf(o0);
    y[(size_t)row * D + tid + 256] = f2bf(o1);
}

__global__ __launch_bounds__(256) void lnr_kernel(float* __restrict__ X,
                                                  const float* __restrict__ P,
                                                  const float* __restrict__ bias,
                                                  unsigned short* __restrict__ y,
                                                  const float* __restrict__ g,
                                                  const float* __restrict__ bb)
{
    int row = blockIdx.x, tid = threadIdx.x;
    float v0 = X[(size_t)row * D + tid] + bias[tid];
    float v1 = X[(size_t)row * D + tid + 256] + bias[tid + 256];
#pragma unroll
    for (int s = 0; s < 4; s++) {
        v0 += P[((size_t)s * NT + row) * D + tid];
        v1 += P[((size_t)s * NT + row) * D + tid + 256];
    }
    X[(size_t)row * D + tid] = v0;
    X[(size_t)row * D + tid + 256] = v1;
    float o0, o1;
    ln_vals_k(v0, v1, g, bb, &o0, &o1, tid);
    y[(size_t)row * D + tid] = f2bf(o0);
    y[(size_t)row * D + tid + 256] = f2bf(o1);
}

__global__ __launch_bounds__(256) void final_lnr_kernel(const float* __restrict__ X,
                                                        const float* __restrict__ P,
                                                        const float* __restrict__ bias,
                                                        float* __restrict__ out,
                                                        const float* __restrict__ g,
                                                        const float* __restrict__ bb)
{
    int row = blockIdx.x, tid = threadIdx.x;   // row = b*T + t
    int b = row >> 8, t = row & (T - 1);
    float v0 = X[(size_t)row * D + tid] + bias[tid];
    float v1 = X[(size_t)row * D + tid + 256] + bias[tid + 256];
#pragma unroll
    for (int s = 0; s < 4; s++) {
        v0 += P[((size_t)s * NT + row) * D + tid];
        v1 += P[((size_t)s * NT + row) * D + tid + 256];
    }
    float o0, o1;
    ln_vals_k(v0, v1, g, bb, &o0, &o1, tid);
    float* op = out + ((size_t)t * B + b) * D;
    op[tid] = o0;
    op[tid + 256] = o1;
}

__global__ __launch_bounds__(256) void convert_all_kernel(
    const float* __restrict__ Wq, const float* __restrict__ Wk, const float* __restrict__ Wv,
    const float* __restrict__ Wo, const float* __restrict__ W1, const float* __restrict__ W2,
    const float* __restrict__ bq, const float* __restrict__ bk, const float* __restrict__ bv,
    const float* __restrict__ rel,
    unsigned short* __restrict__ WQKVb, unsigned short* __restrict__ Wob,
    unsigned short* __restrict__ W1b, unsigned short* __restrict__ W2b,
    unsigned short* __restrict__ relb,
    float* __restrict__ bqkv)
{
    int l = blockIdx.y;
    int g = blockIdx.x * 256 + threadIdx.x;   // 0 .. 396287
    const float* src; unsigned short* dst;
    bool zero = false;
    if (g < 98304) {
        int e = g * 8; int piece = e >> 18; int rem = e & 262143;
        src = (piece == 0 ? Wq : piece == 1 ? Wk : Wv) + (size_t)l * 262144 + rem;
        dst = WQKVb + (size_t)l * 786432 + e;
    } else if (g < 131072) {
        int e = (g - 98304) * 8;
        src = Wo + (size_t)l * 262144 + e; dst = Wob + (size_t)l * 262144 + e;
    } else if (g < 262144) {
        int e = (g - 131072) * 8;
        src = W1 + (size_t)l * 1048576 + e; dst = W1b + (size_t)l * 1048576 + e;
    } else if (g < 393216) {
        int e = (g - 262144) * 8;
        src = W2 + (size_t)l * 1048576 + e; dst = W2b + (size_t)l * 1048576 + e;
    } else {
        int e = (g - 393216) * 8;             // 48 x 512 rel table
        int row = e >> 9, cc = e & 511;
        dst = relb + (size_t)l * 24576 + e;
        if (row < BUCKETS + 1) src = rel + ((size_t)l * (BUCKETS + 1) + row) * 512 + cc;
        else { src = nullptr; zero = true; }
    }
    uint4 o;
    if (zero) { o.x = o.y = o.z = o.w = 0u; }
    else {
        float4 x = *(const float4*)src, y = *(const float4*)(src + 4);
        o.x = (unsigned)f2bf(x.x) | ((unsigned)f2bf(x.y) << 16);
        o.y = (unsigned)f2bf(x.z) | ((unsigned)f2bf(x.w) << 16);
        o.z = (unsigned)f2bf(y.x) | ((unsigned)f2bf(y.y) << 16);
        o.w = (unsigned)f2bf(y.z) | ((unsigned)f2bf(y.w) << 16);
    }
    *(uint4*)dst = o;
    if (g < 3 * D) {
        int piece = g >> 9, r2 = g & 511;
        bqkv[l * 1536 + g] = (piece == 0 ? bq : piece == 1 ? bk : bv)[l * 512 + r2];
    }
}

template <bool RELU, bool OUTBF16>
__global__ __launch_bounds__(256) void mgemm_kernel(
    const unsigned short* __restrict__ A,
    const unsigned short* __restrict__ W,
    const float* __restrict__ bias,
    void* __restrict__ Cv,
    int N, int M, int K)
{
    __shared__ short smA[2][128 * 32];
    __shared__ short smB[2][128 * 32];
    int tid = threadIdx.x;
    int bn = blockIdx.y * 128;
    int bm = blockIdx.x * 128;
    const unsigned short* Ab = A + (size_t)bn * K;
    const unsigned short* Wb = W + (size_t)bm * K;

    f32x4 acc[4][4];
#pragma unroll
    for (int i = 0; i < 4; i++)
#pragma unroll
        for (int j = 0; j < 4; j++) acc[i][j] = (f32x4){0.f, 0.f, 0.f, 0.f};

    const int c0 = tid, c1 = tid + 256;
    const int r0 = c0 >> 2, p0 = c0 & 3, l0 = p0 ^ ((r0 >> 1) & 3);
    const int r1 = c1 >> 2, p1 = c1 & 3, l1 = p1 ^ ((r1 >> 1) & 3);

    auto stage = [&](int buf, int k0) {
        stage16(Ab + (size_t)r0 * K + k0 + l0 * 8, &smA[buf][c0 * 8]);
        stage16(Ab + (size_t)r1 * K + k0 + l1 * 8, &smA[buf][c1 * 8]);
        stage16(Wb + (size_t)r0 * K + k0 + l0 * 8, &smB[buf][c0 * 8]);
        stage16(Wb + (size_t)r1 * K + k0 + l1 * 8, &smB[buf][c1 * 8]);
    };

    const int lane = tid & 63;
    const int wv = tid >> 6, wr = wv >> 1, wc = wv & 1;
    int aoff[4], boff[4];
#pragma unroll
    for (int i = 0; i < 4; i++) {
        int ra = wr * 64 + i * 16 + (lane & 15);
        int ca = (lane >> 4) ^ ((ra >> 1) & 3);
        aoff[i] = ra * 32 + ca * 8;
        int rb = wc * 64 + i * 16 + (lane & 15);
        int cb = (lane >> 4) ^ ((rb >> 1) & 3);
        boff[i] = rb * 32 + cb * 8;
    }

    stage(0, 0);
    const int nkt = K >> 5;
    for (int kt = 0; kt < nkt; ++kt) {
        __syncthreads();
        int cur = kt & 1;
        if (kt + 1 < nkt) stage(cur ^ 1, (kt + 1) << 5);
        const short* sa = smA[cur];
        const short* sb = smB[cur];
        bf16x8 af[4], bfr[4];
#pragma unroll
        for (int i = 0; i < 4; i++) af[i] = *(const bf16x8*)(sa + aoff[i]);
#pragma unroll
        for (int j = 0; j < 4; j++) bfr[j] = *(const bf16x8*)(sb + boff[j]);
#pragma unroll
        for (int i = 0; i < 4; i++)
#pragma unroll
            for (int j = 0; j < 4; j++)
                acc[i][j] = __builtin_amdgcn_mfma_f32_16x16x32_bf16(af[i], bfr[j], acc[i][j], 0, 0, 0);
    }

#pragma unroll
    for (int j = 0; j < 4; j++) {
        int col = bm + wc * 64 + j * 16 + (lane & 15);
        float bval = bias[col];
#pragma unroll
        for (int i = 0; i < 4; i++) {
            f32x4 v = acc[i][j];
#pragma unroll
            for (int r = 0; r < 4; r++) {
                int row = bn + wr * 64 + i * 16 + (lane >> 4) * 4 + r;
                float val = v[r] + bval;
                if (RELU) val = fmaxf(val, 0.f);
                if (OUTBF16) ((unsigned short*)Cv)[(size_t)row * M + col] = f2bf(val);
                else         ((float*)Cv)[(size_t)row * M + col] = val;
            }
        }
    }
}

__global__ __launch_bounds__(256) void mgemm_splitk_kernel(
    const unsigned short* __restrict__ A,
    const unsigned short* __restrict__ W,
    float* __restrict__ P,
    int N, int M, int K, int Ksub)
{
    __shared__ short smA[2][128 * 32];
    __shared__ short smB[2][128 * 32];
    int tid = threadIdx.x;
    int s = blockIdx.z;
    int bn = blockIdx.y * 128;
    int bm = blockIdx.x * 128;
    const unsigned short* Ab = A + (size_t)bn * K + s * Ksub;
    const unsigned short* Wb = W + (size_t)bm * K + s * Ksub;

    f32x4 acc[4][4];
#pragma unroll
    for (int i = 0; i < 4; i++)
#pragma unroll
        for (int j = 0; j < 4; j++) acc[i][j] = (f32x4){0.f, 0.f, 0.f, 0.f};

    const int c0 = tid, c1 = tid + 256;
    const int r0 = c0 >> 2, p0 = c0 & 3, l0 = p0 ^ ((r0 >> 1) & 3);
    const int r1 = c1 >> 2, p1 = c1 & 3, l1 = p1 ^ ((r1 >> 1) & 3);

    auto stage = [&](int buf, int k0) {
        stage16(Ab + (size_t)r0 * K + k0 + l0 * 8, &smA[buf][c0 * 8]);
        stage16(Ab + (size_t)r1 * K + k0 + l1 * 8, &smA[buf][c1 * 8]);
        stage16(Wb + (size_t)r0 * K + k0 + l0 * 8, &smB[buf][c0 * 8]);
        stage16(Wb + (size_t)r1 * K + k0 + l1 * 8, &smB[buf][c1 * 8]);
    };

    const int lane = tid & 63;
    const int wv = tid >> 6, wr = wv >> 1, wc = wv & 1;
    int aoff[4], boff[4];
#pragma unroll
    for (int i = 0; i < 4; i++) {
        int ra = wr * 64 + i * 16 + (lane & 15);
        int ca = (lane >> 4) ^ ((ra >> 1) & 3);
        aoff[i] = ra * 32 + ca * 8;
        int rb = wc * 64 + i * 16 + (lane & 15);
        int cb = (lane >> 4) ^ ((rb >> 1) & 3);
        boff[i] = rb * 32 + cb * 8;
    }

    stage(0, 0);
    const int nkt = Ksub >> 5;
    for (int kt = 0; kt < nkt; ++kt) {
        __syncthreads();
        int cur = kt & 1;
        if (kt + 1 < nkt) stage(cur ^ 1, (kt + 1) << 5);
        const short* sa = smA[cur];
        const short* sb = smB[cur];
        bf16x8 af[4], bfr[4];
#pragma unroll
        for (int i = 0; i < 4; i++) af[i] = *(const bf16x8*)(sa + aoff[i]);
#pragma unroll
        for (int j = 0; j < 4; j++) bfr[j] = *(const bf16x8*)(sb + boff[j]);
#pragma unroll
        for (int i = 0; i < 4; i++)
#pragma unroll
            for (int j = 0; j < 4; j++)
                acc[i][j] = __builtin_amdgcn_mfma_f32_16x16x32_bf16(af[i], bfr[j], acc[i][j], 0, 0, 0);
    }

#pragma unroll
    for (int j = 0; j < 4; j++) {
        int col = bm + wc * 64 + j * 16 + (lane & 15);
#pragma unroll
        for (int i = 0; i < 4; i++) {
            f32x4 v = acc[i][j];
#pragma unroll
            for (int r = 0; r < 4; r++) {
                int row = bn + wr * 64 + i * 16 + (lane >> 4) * 4 + r;
                P[((size_t)s * NT + row) * M + col] = v[r];
            }
        }
    }
}

__global__ __launch_bounds__(256) void vtrans_kernel(const unsigned short* __restrict__ qkv,
                                                     unsigned short* __restrict__ vt)
{
    __shared__ unsigned short tile[64 * 66];
    int bh = blockIdx.x, b = bh >> 3, h = bh & 7;
    int kc = blockIdx.y * 64;
    int tid = threadIdx.x;
    int r = tid >> 2, c0 = (tid & 3) * 16;
    const unsigned short* rp = qkv + (size_t)(b * T + kc + r) * QKVLD + 2 * D + h * 64 + c0;
    uint4 w0 = *(const uint4*)rp;
    uint4 w1 = *(const uint4*)(rp + 8);
    unsigned short* tp = &tile[r * 66 + c0];
    unsigned int ww[8] = {w0.x, w0.y, w0.z, w0.w, w1.x, w1.y, w1.z, w1.w};
#pragma unroll
    for (int e = 0; e < 8; e++) {
        tp[2 * e]     = (unsigned short)(ww[e] & 0xffffu);
        tp[2 * e + 1] = (unsigned short)(ww[e] >> 16);
    }
    __syncthreads();
    int d = tid >> 2, k0 = (tid & 3) * 16;
    unsigned int outw[8];
#pragma unroll
    for (int i = 0; i < 8; i++) {
        unsigned int lo = tile[(k0 + 2 * i) * 66 + d];
        unsigned int hi = tile[(k0 + 2 * i + 1) * 66 + d];
        outw[i] = lo | (hi << 16);
    }
    unsigned short* op = vt + (size_t)(bh * 64 + d) * 256 + kc + k0;
    *(uint4*)op = *(uint4*)&outw[0];
    *(uint4*)(op + 8) = *(uint4*)&outw[4];
}

__global__ __launch_bounds__(256) void fattn_kernel(
    const unsigned short* __restrict__ qkv,
    const unsigned short* __restrict__ vt,
    const unsigned short* __restrict__ relb,
    const float* __restrict__ uvec,
    const float* __restrict__ vvec,
    const int* __restrict__ dist,
    const int* __restrict__ lengths,
    unsigned short* __restrict__ ctx)
{
    __shared__ unsigned short Ps[4][16][256];
    __shared__ float Qrel[4][16][49];

    int bh = blockIdx.x, b = bh >> 3, h = bh & 7;
    int qi0 = blockIdx.y * 64;
    int tid = threadIdx.x, w = tid >> 6, lane = tid & 63;
    int l15 = lane & 15, g = lane >> 4;
    int qr = qi0 + w * 16;

    const unsigned short* qbase = qkv + (size_t)(b * T + qr + l15) * QKVLD + h * 64 + g * 8;
    bf16x8 qa0 = *(const bf16x8*)(qbase);
    bf16x8 qa1 = *(const bf16x8*)(qbase + 32);

    bf16x8 qu0, qu1;
    {
        const float* up = uvec + h * 64 + g * 8;
        float ua0[8], ua1[8];
        *(float4*)&ua0[0] = *(const float4*)(up);
        *(float4*)&ua0[4] = *(const float4*)(up + 4);
        *(float4*)&ua1[0] = *(const float4*)(up + 32);
        *(float4*)&ua1[4] = *(const float4*)(up + 36);
#pragma unroll
        for (int e = 0; e < 8; e++) {
            qu0[e] = (short)f2bf(0.125f * bf2f((unsigned short)qa0[e]) + ua0[e]);
            qu1[e] = (short)f2bf(0.125f * bf2f((unsigned short)qa1[e]) + ua1[e]);
        }
    }

    {
        const float* vp = vvec + h * 64 + g * 8;
        float va0[8], va1[8];
        *(float4*)&va0[0] = *(const float4*)(vp);
        *(float4*)&va0[4] = *(const float4*)(vp + 4);
        *(float4*)&va1[0] = *(const float4*)(vp + 32);
        *(float4*)&va1[4] = *(const float4*)(vp + 36);
        bf16x8 qh0, qh1;
#pragma unroll
        for (int e = 0; e < 8; e++) {
            qh0[e] = (short)f2bf(0.125f * bf2f((unsigned short)qa0[e]) + va0[e]);
            qh1[e] = (short)f2bf(0.125f * bf2f((unsigned short)qa1[e]) + va1[e]);
        }
        f32x4 qacc[3];
#pragma unroll
        for (int j = 0; j < 3; j++) qacc[j] = (f32x4){0.f, 0.f, 0.f, 0.f};
#pragma unroll
        for (int j = 0; j < 3; j++) {
            const unsigned short* rp = relb + (size_t)(j * 16 + l15) * 512 + h * 64 + g * 8;
            bf16x8 rr0 = *(const bf16x8*)(rp);
            bf16x8 rr1 = *(const bf16x8*)(rp + 32);
            qacc[j] = __builtin_amdgcn_mfma_f32_16x16x32_bf16(qh0, rr0, qacc[j], 0, 0, 0);
            qacc[j] = __builtin_amdgcn_mfma_f32_16x16x32_bf16(qh1, rr1, qacc[j], 0, 0, 0);
        }
#pragma unroll
        for (int j = 0; j < 3; j++)
#pragma unroll
            for (int r = 0; r < 4; r++)
                Qrel[w][g * 4 + r][j * 16 + l15] = qacc[j][r];
    }

    f32x4 acc[16];
#pragma unroll
    for (int j = 0; j < 16; j++) acc[j] = (f32x4){0.f, 0.f, 0.f, 0.f};
    const unsigned short* kbase = qkv + (size_t)(b * T) * QKVLD + 512 + h * 64 + g * 8;
#pragma unroll
    for (int j = 0; j < 16; j++) {
        const unsigned short* kp = kbase + (size_t)(j * 16 + l15) * QKVLD;
        bf16x8 k0 = *(const bf16x8*)(kp);
        bf16x8 k1 = *(const bf16x8*)(kp + 32);
        acc[j] = __builtin_amdgcn_mfma_f32_16x16x32_bf16(qu0, k0, acc[j], 0, 0, 0);
        acc[j] = __builtin_amdgcn_mfma_f32_16x16x32_bf16(qu1, k1, acc[j], 0, 0, 0);
    }

    int len = lengths[b];
    float rinv[4];
    const int* db = dist + (size_t)b * T * T;
#pragma unroll
    for (int r = 0; r < 4; r++) {
        int rowloc = g * 4 + r;
        int qrow = qr + rowloc;
        const int* dpr = db + (size_t)qrow * T;
        float m = -3.0e38f;
#pragma unroll
        for (int j = 0; j < 16; j++) {
            int ki = j * 16 + l15;
            int dv = dpr[ki];
            float s = acc[j][r] + Qrel[w][rowloc][dv];
            s = (ki < len) ? s : -1.0e30f;
            acc[j][r] = s;
            m = fmaxf(m, s);
        }
#pragma unroll
        for (int o = 8; o; o >>= 1) m = fmaxf(m, __shfl_xor(m, o));
        float sum = 0.f;
#pragma unroll
        for (int j = 0; j < 16; j++) {
            int ki = j * 16 + l15;
            float p = __expf(acc[j][r] - m);
            sum += p;
            int cph = ((ki >> 3) ^ (rowloc & 7));
            Ps[w][rowloc][cph * 8 + (ki & 7)] = f2bf(p);
        }
#pragma unroll
        for (int o = 8; o; o >>= 1) sum += __shfl_xor(sum, o);
        rinv[r] = 1.0f / sum;
    }

    f32x4 oacc[4];
#pragma unroll
    for (int j = 0; j < 4; j++) oacc[j] = (f32x4){0.f, 0.f, 0.f, 0.f};
    const unsigned short* vtb = vt + (size_t)bh * 64 * 256;
#pragma unroll
    for (int ks = 0; ks < 8; ks++) {
        int c = ks * 4 + g;
        int cph = c ^ (l15 & 7);
        bf16x8 pa = *(const bf16x8*)&Ps[w][l15][cph * 8];
#pragma unroll
        for (int j2 = 0; j2 < 4; j2++) {
            bf16x8 vb = *(const bf16x8*)(vtb + (size_t)(j2 * 16 + l15) * 256 + c * 8);
            oacc[j2] = __builtin_amdgcn_mfma_f32_16x16x32_bf16(pa, vb, oacc[j2], 0, 0, 0);
        }
    }

#pragma unroll
    for (int j2 = 0; j2 < 4; j2++) {
#pragma unroll
        for (int r = 0; r < 4; r++) {
            int qrow = qr + g * 4 + r;
            int dcol = j2 * 16 + l15;
            ctx[(size_t)(b * T + qrow) * D + h * 64 + dcol] = f2bf(oacc[j2][r] * rinv[r]);
        }
    }
}

// ===========================================================================
// PART 2: cooperative mega-kernel (round-6) — fast path if launch succeeds
// ===========================================================================

struct SMem {
    union U {
        struct { short A[2][4096]; short Bv[2][4096]; } g;
        struct { unsigned short Ps[4][16][256]; float Qrel[4][16][49]; } at;
        struct { unsigned short tile[64 * 66]; } vt;
    } u;
    float red[8];
};

struct MArgs {
    const float* src; const int* lengths; const int* dist;
    const float* uvec; const float* vvec;
    const float* ln1_g; const float* ln1_b;
    const float* bo; const float* fg; const float* fb;
    const float* b1; const float* b2; const float* flg; const float* flb;
    float* X; unsigned short* QKVb; unsigned short* Hb; unsigned short* CTX;
    unsigned short* FF1; unsigned short* VT; float* Pbuf;
    const unsigned short* WQKVb; const unsigned short* Wob;
    const unsigned short* W1b; const unsigned short* W2b;
    const unsigned short* RELb; const float* bqkv;
    float* out;
};

__device__ __forceinline__ void ln_vals_m(float v0, float v1,
                                          const float* __restrict__ g,
                                          const float* __restrict__ bb,
                                          float* o0, float* o1, int tid, float* red)
{
    float s = v0 + v1, q2 = v0 * v0 + v1 * v1;
#pragma unroll
    for (int o = 32; o; o >>= 1) { s += __shfl_xor(s, o); q2 += __shfl_xor(q2, o); }
    int lane = tid & 63, wid = tid >> 6;
    if (lane == 0) { red[wid] = s; red[4 + wid] = q2; }
    __syncthreads();
    s = red[0] + red[1] + red[2] + red[3];
    q2 = red[4] + red[5] + red[6] + red[7];
    __syncthreads();
    float mean = s * (1.f / (float)D);
    float var = q2 * (1.f / (float)D) - mean * mean;
    float rstd = rsqrtf(var + 1e-6f);
    *o0 = (v0 - mean) * rstd * g[tid] + bb[tid];
    *o1 = (v1 - mean) * rstd * g[tid + 256] + bb[tid + 256];
}

__device__ void st_embed_ln(SMem* sm, const MArgs& a, int bid, int tid)
{
    int d0 = tid, d1 = tid + 256;
    float dv0 = expf(-(float)(2 * (d0 >> 1)) * (9.210340371976184f / (float)D));
    float dv1 = expf(-(float)(2 * (d1 >> 1)) * (9.210340371976184f / (float)D));
    for (int i = 0; i < 8; i++) {
        int row = bid * 8 + i;
        int b = row >> 8, t = row & (T - 1);
        float a0 = (float)t * dv0, a1 = (float)t * dv1;
        float pe0 = (d0 & 1) ? cosf(a0) : sinf(a0);
        float pe1 = (d1 & 1) ? cosf(a1) : sinf(a1);
        const float* sp = a.src + ((size_t)t * B + b) * D;
        float v0 = sp[d0] * 22.62741699796952f + pe0;
        float v1 = sp[d1] * 22.62741699796952f + pe1;
        a.X[(size_t)row * D + d0] = v0;
        a.X[(size_t)row * D + d1] = v1;
        float o0, o1;
        ln_vals_m(v0, v1, a.ln1_g, a.ln1_b, &o0, &o1, tid, sm->red);
        a.Hb[(size_t)row * D + d0] = f2bf(o0);
        a.Hb[(size_t)row * D + d1] = f2bf(o1);
    }
}

__device__ void st_lnr(SMem* sm, const MArgs& a, int bid, int tid,
                       const float* __restrict__ bias,
                       const float* __restrict__ g, const float* __restrict__ bb)
{
    for (int i = 0; i < 8; i++) {
        int row = bid * 8 + i;
        float v0 = a.X[(size_t)row * D + tid] + bias[tid];
        float v1 = a.X[(size_t)row * D + tid + 256] + bias[tid + 256];
#pragma unroll
        for (int s = 0; s < 4; s++) {
            v0 += a.Pbuf[((size_t)s * NT + row) * D + tid];
            v1 += a.Pbuf[((size_t)s * NT + row) * D + tid + 256];
        }
        a.X[(size_t)row * D + tid] = v0;
        a.X[(size_t)row * D + tid + 256] = v1;
        float o0, o1;
        ln_vals_m(v0, v1, g, bb, &o0, &o1, tid, sm->red);
        a.Hb[(size_t)row * D + tid] = f2bf(o0);
        a.Hb[(size_t)row * D + tid + 256] = f2bf(o1);
    }
}

__device__ void st_final(SMem* sm, const MArgs& a, int bid, int tid)
{
    const float* bias = a.b2 + (size_t)(L - 1) * D;
    for (int i = 0; i < 8; i++) {
        int row = bid * 8 + i;
        int b = row >> 8, t = row & (T - 1);
        float v0 = a.X[(size_t)row * D + tid] + bias[tid];
        float v1 = a.X[(size_t)row * D + tid + 256] + bias[tid + 256];
#pragma unroll
        for (int s = 0; s < 4; s++) {
            v0 += a.Pbuf[((size_t)s * NT + row) * D + tid];
            v1 += a.Pbuf[((size_t)s * NT + row) * D + tid + 256];
        }
        float o0, o1;
        ln_vals_m(v0, v1, a.flg, a.flb, &o0, &o1, tid, sm->red);
        float* op = a.out + ((size_t)t * B + b) * D;
        op[tid] = o0;
        op[tid + 256] = o1;
    }
}

template <bool RELU>
__device__ void st_gemm(SMem* sm, int unit, int tid,
                        const unsigned short* __restrict__ A,
                        const unsigned short* __restrict__ W,
                        const float* __restrict__ bias,
                        unsigned short* __restrict__ C,
                        int M, int K, int tx, int ntiles)
{
    if (unit >= ntiles) return;
    auto& G = sm->u.g;
    int bm = (unit % tx) * 128, bn = (unit / tx) * 128;
    const unsigned short* Ab = A + (size_t)bn * K;
    const unsigned short* Wb = W + (size_t)bm * K;

    f32x4 acc[4][4];
#pragma unroll
    for (int i = 0; i < 4; i++)
#pragma unroll
        for (int j = 0; j < 4; j++) acc[i][j] = (f32x4){0.f, 0.f, 0.f, 0.f};

    const int c0 = tid, c1 = tid + 256;
    const int r0 = c0 >> 2, p0 = c0 & 3, l0 = p0 ^ ((r0 >> 1) & 3);
    const int r1 = c1 >> 2, p1 = c1 & 3, l1 = p1 ^ ((r1 >> 1) & 3);

    auto stage = [&](int buf, int k0) {
        stage16(Ab + (size_t)r0 * K + k0 + l0 * 8, &G.A[buf][c0 * 8]);
        stage16(Ab + (size_t)r1 * K + k0 + l1 * 8, &G.A[buf][c1 * 8]);
        stage16(Wb + (size_t)r0 * K + k0 + l0 * 8, &G.Bv[buf][c0 * 8]);
        stage16(Wb + (size_t)r1 * K + k0 + l1 * 8, &G.Bv[buf][c1 * 8]);
    };

    const int lane = tid & 63;
    const int wv = tid >> 6, wr = wv >> 1, wc = wv & 1;
    int aoff[4], boff[4];
#pragma unroll
    for (int i = 0; i < 4; i++) {
        int ra = wr * 64 + i * 16 + (lane & 15);
        int ca = (lane >> 4) ^ ((ra >> 1) & 3);
        aoff[i] = ra * 32 + ca * 8;
        int rb = wc * 64 + i * 16 + (lane & 15);
        int cb = (lane >> 4) ^ ((rb >> 1) & 3);
        boff[i] = rb * 32 + cb * 8;
    }

    stage(0, 0);
    const int nkt = K >> 5;
    for (int kt = 0; kt < nkt; ++kt) {
        __syncthreads();
        int cur = kt & 1;
        if (kt + 1 < nkt) stage(cur ^ 1, (kt + 1) << 5);
        const short* sa = G.A[cur];
        const short* sb = G.Bv[cur];
        bf16x8 af[4], bfr[4];
#pragma unroll
        for (int i = 0; i < 4; i++) af[i] = *(const bf16x8*)(sa + aoff[i]);
#pragma unroll
        for (int j = 0; j < 4; j++) bfr[j] = *(const bf16x8*)(sb + boff[j]);
#pragma unroll
        for (int i = 0; i < 4; i++)
#pragma unroll
            for (int j = 0; j < 4; j++)
                acc[i][j] = __builtin_amdgcn_mfma_f32_16x16x32_bf16(af[i], bfr[j], acc[i][j], 0, 0, 0);
    }

#pragma unroll
    for (int j = 0; j < 4; j++) {
        int col = bm + wc * 64 + j * 16 + (lane & 15);
        float bval = bias[col];
#pragma unroll
        for (int i = 0; i < 4; i++) {
            f32x4 v = acc[i][j];
#pragma unroll
            for (int r = 0; r < 4; r++) {
                int row = bn + wr * 64 + i * 16 + (lane >> 4) * 4 + r;
                float val = v[r] + bval;
                if (RELU) val = fmaxf(val, 0.f);
                C[(size_t)row * M + col] = f2bf(val);
            }
        }
    }
}

__device__ void st_gemm_sk(SMem* sm, int unit, int tid,
                           const unsigned short* __restrict__ A,
                           const unsigned short* __restrict__ W,
                           float* __restrict__ P,
                           int M, int K, int Ksub)
{
    auto& G = sm->u.g;
    int s = unit >> 6, rem = unit & 63;
    int bm = (rem & 3) * 128, bn = (rem >> 2) * 128;
    const unsigned short* Ab = A + (size_t)bn * K + s * Ksub;
    const unsigned short* Wb = W + (size_t)bm * K + s * Ksub;

    f32x4 acc[4][4];
#pragma unroll
    for (int i = 0; i < 4; i++)
#pragma unroll
        for (int j = 0; j < 4; j++) acc[i][j] = (f32x4){0.f, 0.f, 0.f, 0.f};

    const int c0 = tid, c1 = tid + 256;
    const int r0 = c0 >> 2, p0 = c0 & 3, l0 = p0 ^ ((r0 >> 1) & 3);
    const int r1 = c1 >> 2, p1 = c1 & 3, l1 = p1 ^ ((r1 >> 1) & 3);

    auto stage = [&](int buf, int k0) {
        stage16(Ab + (size_t)r0 * K + k0 + l0 * 8, &G.A[buf][c0 * 8]);
        stage16(Ab + (size_t)r1 * K + k0 + l1 * 8, &G.A[buf][c1 * 8]);
        stage16(Wb + (size_t)r0 * K + k0 + l0 * 8, &G.Bv[buf][c0 * 8]);
        stage16(Wb + (size_t)r1 * K + k0 + l1 * 8, &G.Bv[buf][c1 * 8]);
    };

    const int lane = tid & 63;
    const int wv = tid >> 6, wr = wv >> 1, wc = wv & 1;
    int aoff[4], boff[4];
#pragma unroll
    for (int i = 0; i < 4; i++) {
        int ra = wr * 64 + i * 16 + (lane & 15);
        int ca = (lane >> 4) ^ ((ra >> 1) & 3);
        aoff[i] = ra * 32 + ca * 8;
        int rb = wc * 64 + i * 16 + (lane & 15);
        int cb = (lane >> 4) ^ ((rb >> 1) & 3);
        boff[i] = rb * 32 + cb * 8;
    }

    stage(0, 0);
    const int nkt = Ksub >> 5;
    for (int kt = 0; kt < nkt; ++kt) {
        __syncthreads();
        int cur = kt & 1;
        if (kt + 1 < nkt) stage(cur ^ 1, (kt + 1) << 5);
        const short* sa = G.A[cur];
        const short* sb = G.Bv[cur];
        bf16x8 af[4], bfr[4];
#pragma unroll
        for (int i = 0; i < 4; i++) af[i] = *(const bf16x8*)(sa + aoff[i]);
#pragma unroll
        for (int j = 0; j < 4; j++) bfr[j] = *(const bf16x8*)(sb + boff[j]);
#pragma unroll
        for (int i = 0; i < 4; i++)
#pragma unroll
            for (int j = 0; j < 4; j++)
                acc[i][j] = __builtin_amdgcn_mfma_f32_16x16x32_bf16(af[i], bfr[j], acc[i][j], 0, 0, 0);
    }

#pragma unroll
    for (int j = 0; j < 4; j++) {
        int col = bm + wc * 64 + j * 16 + (lane & 15);
#pragma unroll
        for (int i = 0; i < 4; i++) {
            f32x4 v = acc[i][j];
#pragma unroll
            for (int r = 0; r < 4; r++) {
                int row = bn + wr * 64 + i * 16 + (lane >> 4) * 4 + r;
                P[((size_t)s * NT + row) * M + col] = v[r];
            }
        }
    }
}

__device__ void st_vtrans(SMem* sm, int unit, int tid,
                          const unsigned short* __restrict__ qkv,
                          unsigned short* __restrict__ vt)
{
    unsigned short* tile = sm->u.vt.tile;
    int bh = unit & 63, b = bh >> 3, h = bh & 7;
    int kc = (unit >> 6) * 64;
    int r = tid >> 2, c0 = (tid & 3) * 16;
    const unsigned short* rp = qkv + (size_t)(b * T + kc + r) * QKVLD + 2 * D + h * 64 + c0;
    uint4 w0 = *(const uint4*)rp;
    uint4 w1 = *(const uint4*)(rp + 8);
    unsigned short* tp = &tile[r * 66 + c0];
    unsigned int ww[8] = {w0.x, w0.y, w0.z, w0.w, w1.x, w1.y, w1.z, w1.w};
#pragma unroll
    for (int e = 0; e < 8; e++) {
        tp[2 * e]     = (unsigned short)(ww[e] & 0xffffu);
        tp[2 * e + 1] = (unsigned short)(ww[e] >> 16);
    }
    __syncthreads();
    int d = tid >> 2, k0 = (tid & 3) * 16;
    unsigned int outw[8];
#pragma unroll
    for (int i = 0; i < 8; i++) {
        unsigned int lo = tile[(k0 + 2 * i) * 66 + d];
        unsigned int hi = tile[(k0 + 2 * i + 1) * 66 + d];
        outw[i] = lo | (hi << 16);
    }
    unsigned short* op = vt + (size_t)(bh * 64 + d) * 256 + kc + k0;
    *(uint4*)op = *(uint4*)&outw[0];
    *(uint4*)(op + 8) = *(uint4*)&outw[4];
    __syncthreads();
}

__device__ void st_fattn(SMem* sm, int unit, int tid,
                         const unsigned short* __restrict__ qkv,
                         const unsigned short* __restrict__ vt,
                         const unsigned short* __restrict__ relb,
                         const float* __restrict__ uvec,
                         const float* __restrict__ vvec,
                         const int* __restrict__ dist,
                         const int* __restrict__ lengths,
                         unsigned short* __restrict__ ctx)
{
    auto& AT = sm->u.at;
    int bh = unit & 63, b = bh >> 3, h = bh & 7;
    int qi0 = (unit >> 6) * 64;
    int w = tid >> 6, lane = tid & 63;
    int l15 = lane & 15, g = lane >> 4;
    int qr = qi0 + w * 16;

    const unsigned short* qbase = qkv + (size_t)(b * T + qr + l15) * QKVLD + h * 64 + g * 8;
    bf16x8 qa0 = *(const bf16x8*)(qbase);
    bf16x8 qa1 = *(const bf16x8*)(qbase + 32);

    bf16x8 qu0, qu1;
    {
        const float* up = uvec + h * 64 + g * 8;
        float ua0[8], ua1[8];
        *(float4*)&ua0[0] = *(const float4*)(up);
        *(float4*)&ua0[4] = *(const float4*)(up + 4);
        *(float4*)&ua1[0] = *(const float4*)(up + 32);
        *(float4*)&ua1[4] = *(const float4*)(up + 36);
#pragma unroll
        for (int e = 0; e < 8; e++) {
            qu0[e] = (short)f2bf(0.125f * bf2f((unsigned short)qa0[e]) + ua0[e]);
            qu1[e] = (short)f2bf(0.125f * bf2f((unsigned short)qa1[e]) + ua1[e]);
        }
    }

    {
        const float* vp = vvec + h * 64 + g * 8;
        float va0[8], va1[8];
        *(float4*)&va0[0] = *(const float4*)(vp);
        *(float4*)&va0[4] = *(const float4*)(vp + 4);
        *(float4*)&va1[0] = *(const float4*)(vp + 32);
        *(float4*)&va1[4] = *(const float4*)(vp + 36);
        bf16x8 qh0, qh1;
#pragma unroll
        for (int e = 0; e < 8; e++) {
            qh0[e] = (short)f2bf(0.125f * bf2f((unsigned short)qa0[e]) + va0[e]);
            qh1[e] = (short)f2bf(0.125f * bf2f((unsigned short)qa1[e]) + va1[e]);
        }
        f32x4 qacc[3];
#pragma unroll
        for (int j = 0; j < 3; j++) qacc[j] = (f32x4){0.f, 0.f, 0.f, 0.f};
#pragma unroll
        for (int j = 0; j < 3; j++) {
            const unsigned short* rp = relb + (size_t)(j * 16 + l15) * 512 + h * 64 + g * 8;
            bf16x8 rr0 = *(const bf16x8*)(rp);
            bf16x8 rr1 = *(const bf16x8*)(rp + 32);
            qacc[j] = __builtin_amdgcn_mfma_f32_16x16x32_bf16(qh0, rr0, qacc[j], 0, 0, 0);
            qacc[j] = __builtin_amdgcn_mfma_f32_16x16x32_bf16(qh1, rr1, qacc[j], 0, 0, 0);
        }
#pragma unroll
        for (int j = 0; j < 3; j++)
#pragma unroll
            for (int r = 0; r < 4; r++)
                AT.Qrel[w][g * 4 + r][j * 16 + l15] = qacc[j][r];
    }

    f32x4 acc[16];
#pragma unroll
    for (int j = 0; j < 16; j++) acc[j] = (f32x4){0.f, 0.f, 0.f, 0.f};
    const unsigned short* kbase = qkv + (size_t)(b * T) * QKVLD + 512 + h * 64 + g * 8;
#pragma unroll
    for (int j = 0; j < 16; j++) {
        const unsigned short* kp = kbase + (size_t)(j * 16 + l15) * QKVLD;
        bf16x8 k0 = *(const bf16x8*)(kp);
        bf16x8 k1 = *(const bf16x8*)(kp + 32);
        acc[j] = __builtin_amdgcn_mfma_f32_16x16x32_bf16(qu0, k0, acc[j], 0, 0, 0);
        acc[j] = __builtin_amdgcn_mfma_f32_16x16x32_bf16(qu1, k1, acc[j], 0, 0, 0);
    }

    int len = lengths[b];
    float rinv[4];
    const int* db = dist + (size_t)b * T * T;
#pragma unroll
    for (int r = 0; r < 4; r++) {
        int rowloc = g * 4 + r;
        int qrow = qr + rowloc;
        const int* dpr = db + (size_t)qrow * T;
        float m = -3.0e38f;
#pragma unroll
        for (int j = 0; j < 16; j++) {
            int ki = j * 16 + l15;
            int dv = dpr[ki];
            float s = acc[j][r] + AT.Qrel[w][rowloc][dv];
            s = (ki < len) ? s : -1.0e30f;
            acc[j][r] = s;
            m = fmaxf(m, s);
        }
#pragma unroll
        for (int o = 8; o; o >>= 1) m = fmaxf(m, __shfl_xor(m, o));
        float sum = 0.f;
#pragma unroll
        for (int j = 0; j < 16; j++) {
            int ki = j * 16 + l15;
            float p = __expf(acc[j][r] - m);
            sum += p;
            int cph = ((ki >> 3) ^ (rowloc & 7));
            AT.Ps[w][rowloc][cph * 8 + (ki & 7)] = f2bf(p);
        }
#pragma unroll
        for (int o = 8; o; o >>= 1) sum += __shfl_xor(sum, o);
        rinv[r] = 1.0f / sum;
    }

    f32x4 oacc[4];
#pragma unroll
    for (int j = 0; j < 4; j++) oacc[j] = (f32x4){0.f, 0.f, 0.f, 0.f};
    const unsigned short* vtb = vt + (size_t)bh * 64 * 256;
#pragma unroll
    for (int ks = 0; ks < 8; ks++) {
        int c = ks * 4 + g;
        int cph = c ^ (l15 & 7);
        bf16x8 pa = *(const bf16x8*)&AT.Ps[w][l15][cph * 8];
#pragma unroll
        for (int j2 = 0; j2 < 4; j2++) {
            bf16x8 vb = *(const bf16x8*)(vtb + (size_t)(j2 * 16 + l15) * 256 + c * 8);
            oacc[j2] = __builtin_amdgcn_mfma_f32_16x16x32_bf16(pa, vb, oacc[j2], 0, 0, 0);
        }
    }

#pragma unroll
    for (int j2 = 0; j2 < 4; j2++) {
#pragma unroll
        for (int r = 0; r < 4; r++) {
            int qrow = qr + g * 4 + r;
            int dcol = j2 * 16 + l15;
            ctx[(size_t)(b * T + qrow) * D + h * 64 + dcol] = f2bf(oacc[j2][r] * rinv[r]);
        }
    }
}

__global__ void __launch_bounds__(256) mega_kernel(MArgs a)
{
    __shared__ SMem sm;
    cg::grid_group grid = cg::this_grid();
    int bid = blockIdx.x, tid = threadIdx.x;

    st_embed_ln(&sm, a, bid, tid);
    grid.sync();

    for (int l = 0; l < L; ++l) {
        const unsigned short* wqkv = a.WQKVb + (size_t)l * 786432;
        const unsigned short* wob  = a.Wob   + (size_t)l * 262144;
        const unsigned short* w1b  = a.W1b   + (size_t)l * 1048576;
        const unsigned short* w2b  = a.W2b   + (size_t)l * 1048576;
        const unsigned short* relb = a.RELb  + (size_t)l * 24576;
        const float*          bql  = a.bqkv  + (size_t)l * 1536;

        st_gemm<false>(&sm, bid, tid, a.Hb, wqkv, bql, a.QKVb, QKVLD, D, 12, 192);
        grid.sync();

        st_vtrans(&sm, bid, tid, a.QKVb, a.VT);
        grid.sync();

        st_fattn(&sm, bid, tid, a.QKVb, a.VT, relb, a.uvec, a.vvec,
                 a.dist, a.lengths, a.CTX);
        grid.sync();

        st_gemm_sk(&sm, bid, tid, a.CTX, wob, a.Pbuf, D, D, D / 4);
        grid.sync();

        st_lnr(&sm, a, bid, tid, a.bo + (size_t)l * D, a.fg + l * D, a.fb + l * D);
        grid.sync();

        st_gemm<true>(&sm, bid, tid, a.Hb, w1b, a.b1 + (size_t)l * DFF, a.FF1, DFF, D, 16, 256);
        grid.sync();

        st_gemm_sk(&sm, bid, tid, a.FF1, w2b, a.Pbuf, D, DFF, DFF / 4);
        grid.sync();

        if (l < L - 1) {
            st_lnr(&sm, a, bid, tid, a.b2 + (size_t)l * D,
                   a.ln1_g + (l + 1) * D, a.ln1_b + (l + 1) * D);
            grid.sync();
        }
    }

    st_final(&sm, a, bid, tid);
}

// ===========================================================================
// launch: convert weights, then TRY cooperative mega; on error fall back to
// the proven multi-kernel sequence (identical math either way).
// ===========================================================================
extern "C" void kernel_launch(void* const* d_in, const int* in_sizes, int n_in,
                              void* d_out, int out_size, void* d_ws, size_t ws_size,
                              hipStream_t stream)
{
    const float* src     = (const float*)d_in[0];
    const int*   lengths = (const int*)d_in[1];
    const int*   dist    = (const int*)d_in[2];
    const float* u       = (const float*)d_in[3];
    const float* v       = (const float*)d_in[4];
    const float* ln1_g   = (const float*)d_in[5];
    const float* ln1_b   = (const float*)d_in[6];
    const float* Wq      = (const float*)d_in[7];
    const float* Wk      = (const float*)d_in[8];
    const float* Wv      = (const float*)d_in[9];
    const float* Wo      = (const float*)d_in[10];
    const float* bq      = (const float*)d_in[11];
    const float* bk      = (const float*)d_in[12];
    const float* bv      = (const float*)d_in[13];
    const float* bo      = (const float*)d_in[14];
    const float* rel     = (const float*)d_in[15];
    const float* fg      = (const float*)d_in[16];
    const float* fb      = (const float*)d_in[17];
    const float* W1      = (const float*)d_in[18];
    const float* b1      = (const float*)d_in[19];
    const float* W2      = (const float*)d_in[20];
    const float* b2      = (const float*)d_in[21];
    const float* flg     = (const float*)d_in[22];
    const float* flb     = (const float*)d_in[23];

    float* ws = (float*)d_ws;
    float*          X     = ws;                                   // 1048576 f
    unsigned short* QKVb  = (unsigned short*)(ws + 1048576);      // 3145728 bf16
    unsigned short* Hb    = (unsigned short*)(ws + 2621440);      // 1048576 bf16
    unsigned short* CTX   = (unsigned short*)(ws + 3145728);      // 1048576 bf16
    unsigned short* FF1   = (unsigned short*)(ws + 3670016);      // 4194304 bf16
    unsigned short* VT    = (unsigned short*)(ws + 5767168);      // 1048576 bf16
    float*          Pbuf  = ws + 6291456;                         // 4x2048x512 f32
    unsigned short* WQKVb = (unsigned short*)(ws + 10485760);     // 4x786432 bf16
    unsigned short* Wob   = (unsigned short*)(ws + 12058624);     // 4x262144 bf16
    unsigned short* W1b   = (unsigned short*)(ws + 12582912);     // 4x1048576 bf16
    unsigned short* W2b   = (unsigned short*)(ws + 14680064);     // 4x1048576 bf16
    unsigned short* RELb  = (unsigned short*)(ws + 16777216);     // 4x24576 bf16
    float*          bqkv  = ws + 16826368;                        // 4x1536 f

    convert_all_kernel<<<dim3(1548, L), 256, 0, stream>>>(
        Wq, Wk, Wv, Wo, W1, W2, bq, bk, bv, rel,
        WQKVb, Wob, W1b, W2b, RELb, bqkv);

    MArgs a;
    a.src = src; a.lengths = lengths; a.dist = dist;
    a.uvec = u; a.vvec = v;
    a.ln1_g = ln1_g; a.ln1_b = ln1_b;
    a.bo = bo; a.fg = fg; a.fb = fb;
    a.b1 = b1; a.b2 = b2; a.flg = flg; a.flb = flb;
    a.X = X; a.QKVb = QKVb; a.Hb = Hb; a.CTX = CTX;
    a.FF1 = FF1; a.VT = VT; a.Pbuf = Pbuf;
    a.WQKVb = WQKVb; a.Wob = Wob; a.W1b = W1b; a.W2b = W2b;
    a.RELb = RELb; a.bqkv = bqkv;
    a.out = (float*)d_out;

    void* kargs[] = { (void*)&a };
    hipError_t err = hipLaunchCooperativeKernel((const void*)mega_kernel,
                                                dim3(256), dim3(256),
                                                kargs, 0, stream);
    if (err == hipSuccess) return;
    (void)hipGetLastError();   // clear sticky error, use fallback path

    embed_kernel<<<T, 256, 0, stream>>>(src, X);

    for (int l = 0; l < L; l++) {
        const unsigned short* wqkv = WQKVb + (size_t)l * 786432;
        const unsigned short* wob  = Wob   + (size_t)l * 262144;
        const unsigned short* w1b  = W1b   + (size_t)l * 1048576;
        const unsigned short* w2b  = W2b   + (size_t)l * 1048576;
        const unsigned short* relb = RELb  + (size_t)l * 24576;
        const float*          bql  = bqkv  + (size_t)l * 1536;

        if (l == 0)
            ln_kernel<<<NT, 256, 0, stream>>>(X, Hb, ln1_g, ln1_b);
        else
            lnr_kernel<<<NT, 256, 0, stream>>>(X, Pbuf, b2 + (size_t)(l - 1) * D,
                                               Hb, ln1_g + l * D, ln1_b + l * D);

        mgemm_kernel<false, true><<<dim3(12, 16), 256, 0, stream>>>(
            Hb, wqkv, bql, QKVb, NT, QKVLD, D);

        vtrans_kernel<<<dim3(64, 4), 256, 0, stream>>>(QKVb, VT);

        fattn_kernel<<<dim3(B * H, T / 64), 256, 0, stream>>>(
            QKVb, VT, relb, u, v, dist, lengths, CTX);

        mgemm_splitk_kernel<<<dim3(4, 16, 4), 256, 0, stream>>>(
            CTX, wob, Pbuf, NT, D, D, D / 4);

        lnr_kernel<<<NT, 256, 0, stream>>>(X, Pbuf, bo + (size_t)l * D,
                                           Hb, fg + l * D, fb + l * D);

        mgemm_kernel<true, true><<<dim3(16, 16), 256, 0, stream>>>(
            Hb, w1b, b1 + (size_t)l * DFF, FF1, NT, DFF, D);

        mgemm_splitk_kernel<<<dim3(4, 16, 4), 256, 0, stream>>>(
            FF1, w2b, Pbuf, NT, D, DFF, DFF / 4);
    }

    final_lnr_kernel<<<NT, 256, 0, stream>>>(X, Pbuf, b2 + (size_t)(L - 1) * D,
                                             (float*)d_out, flg, flb);
}

// Round 9
// 518.901 us; speedup vs baseline: 3.3238x; 3.3238x over previous
//
#include <hip/hip_runtime.h>
#include <hip/hip_bf16.h>
#include <math.h>

constexpr int L = 4, D = 512, H = 8, DFF = 2048, T = 256, B = 8, BUCKETS = 32;
constexpr int DH = D / H;          // 64
constexpr int NT = B * T;          // 2048 rows
constexpr int QKVLD = 3 * D;       // 1536

typedef __attribute__((ext_vector_type(8))) short bf16x8;
typedef __attribute__((ext_vector_type(4))) float f32x4;

__device__ __forceinline__ unsigned short f2bf(float f) {
    unsigned int x = __float_as_uint(f);
    return (unsigned short)((x + 0x7fffu + ((x >> 16) & 1u)) >> 16);
}
__device__ __forceinline__ float bf2f(unsigned short u) {
    return __uint_as_float((unsigned int)u << 16);
}

__device__ __forceinline__ void stage16(const unsigned short* g, short* l) {
    __builtin_amdgcn_global_load_lds((const __attribute__((address_space(1))) unsigned int*)g,
                                     (__attribute__((address_space(3))) unsigned int*)l,
                                     16, 0, 0);
}

// ---------------------------------------------------------------------------
// LayerNorm core (block = one row of 512, 2 vals/thread)
// ---------------------------------------------------------------------------
__device__ __forceinline__ void ln_vals_k(float v0, float v1,
                                          const float* __restrict__ g,
                                          const float* __restrict__ bb,
                                          float* o0, float* o1, int tid)
{
    float s = v0 + v1, q2 = v0 * v0 + v1 * v1;
#pragma unroll
    for (int o = 32; o; o >>= 1) { s += __shfl_xor(s, o); q2 += __shfl_xor(q2, o); }
    __shared__ float rs[4], rq[4];
    int lane = tid & 63, wid = tid >> 6;
    if (lane == 0) { rs[wid] = s; rq[wid] = q2; }
    __syncthreads();
    s = rs[0] + rs[1] + rs[2] + rs[3];
    q2 = rq[0] + rq[1] + rq[2] + rq[3];
    float mean = s * (1.f / (float)D);
    float var = q2 * (1.f / (float)D) - mean * mean;
    float rstd = rsqrtf(var + 1e-6f);
    *o0 = (v0 - mean) * rstd * g[tid] + bb[tid];
    *o1 = (v1 - mean) * rstd * g[tid + 256] + bb[tid + 256];
}

// ---------------------------------------------------------------------------
// embed + layer-0 LN fused: one block per row (b*T+t).
// ---------------------------------------------------------------------------
__global__ __launch_bounds__(256) void embed_ln_kernel(const float* __restrict__ src,
                                                       float* __restrict__ X,
                                                       unsigned short* __restrict__ Hb,
                                                       const float* __restrict__ g,
                                                       const float* __restrict__ bb)
{
    int row = blockIdx.x, tid = threadIdx.x;
    int b = row >> 8, t = row & (T - 1);
    int d0 = tid, d1 = tid + 256;
    float dv0 = expf(-(float)(2 * (d0 >> 1)) * (9.210340371976184f / (float)D));
    float dv1 = expf(-(float)(2 * (d1 >> 1)) * (9.210340371976184f / (float)D));
    float a0 = (float)t * dv0, a1 = (float)t * dv1;
    float pe0 = (d0 & 1) ? cosf(a0) : sinf(a0);
    float pe1 = (d1 & 1) ? cosf(a1) : sinf(a1);
    const float* sp = src + ((size_t)t * B + b) * D;
    float v0 = sp[d0] * 22.62741699796952f + pe0;
    float v1 = sp[d1] * 22.62741699796952f + pe1;
    X[(size_t)row * D + d0] = v0;
    X[(size_t)row * D + d1] = v1;
    float o0, o1;
    ln_vals_k(v0, v1, g, bb, &o0, &o1, tid);
    Hb[(size_t)row * D + d0] = f2bf(o0);
    Hb[(size_t)row * D + d1] = f2bf(o1);
}

// ---------------------------------------------------------------------------
// reduce-LN: xn = X + bias + sum_s P[s]; X = xn; y = bf16(LN(xn))
// ---------------------------------------------------------------------------
__global__ __launch_bounds__(256) void lnr_kernel(float* __restrict__ X,
                                                  const float* __restrict__ P,
                                                  const float* __restrict__ bias,
                                                  unsigned short* __restrict__ y,
                                                  const float* __restrict__ g,
                                                  const float* __restrict__ bb)
{
    int row = blockIdx.x, tid = threadIdx.x;
    float v0 = X[(size_t)row * D + tid] + bias[tid];
    float v1 = X[(size_t)row * D + tid + 256] + bias[tid + 256];
#pragma unroll
    for (int s = 0; s < 4; s++) {
        v0 += P[((size_t)s * NT + row) * D + tid];
        v1 += P[((size_t)s * NT + row) * D + tid + 256];
    }
    X[(size_t)row * D + tid] = v0;
    X[(size_t)row * D + tid + 256] = v1;
    float o0, o1;
    ln_vals_k(v0, v1, g, bb, &o0, &o1, tid);
    y[(size_t)row * D + tid] = f2bf(o0);
    y[(size_t)row * D + tid + 256] = f2bf(o1);
}

// final reduce-LN: out(T,B,D) = LN(X + bias + sum_s P[s])
__global__ __launch_bounds__(256) void final_lnr_kernel(const float* __restrict__ X,
                                                        const float* __restrict__ P,
                                                        const float* __restrict__ bias,
                                                        float* __restrict__ out,
                                                        const float* __restrict__ g,
                                                        const float* __restrict__ bb)
{
    int row = blockIdx.x, tid = threadIdx.x;   // row = b*T + t
    int b = row >> 8, t = row & (T - 1);
    float v0 = X[(size_t)row * D + tid] + bias[tid];
    float v1 = X[(size_t)row * D + tid + 256] + bias[tid + 256];
#pragma unroll
    for (int s = 0; s < 4; s++) {
        v0 += P[((size_t)s * NT + row) * D + tid];
        v1 += P[((size_t)s * NT + row) * D + tid + 256];
    }
    float o0, o1;
    ln_vals_k(v0, v1, g, bb, &o0, &o1, tid);
    float* op = out + ((size_t)t * B + b) * D;
    op[tid] = o0;
    op[tid + 256] = o1;
}

// ---------------------------------------------------------------------------
// weight f32->bf16 conversion for ALL layers (grid 1548 x L)
// ---------------------------------------------------------------------------
__global__ __launch_bounds__(256) void convert_all_kernel(
    const float* __restrict__ Wq, const float* __restrict__ Wk, const float* __restrict__ Wv,
    const float* __restrict__ Wo, const float* __restrict__ W1, const float* __restrict__ W2,
    const float* __restrict__ bq, const float* __restrict__ bk, const float* __restrict__ bv,
    const float* __restrict__ rel,
    unsigned short* __restrict__ WQKVb, unsigned short* __restrict__ Wob,
    unsigned short* __restrict__ W1b, unsigned short* __restrict__ W2b,
    unsigned short* __restrict__ relb,
    float* __restrict__ bqkv)
{
    int l = blockIdx.y;
    int g = blockIdx.x * 256 + threadIdx.x;   // 0 .. 396287
    const float* src; unsigned short* dst;
    bool zero = false;
    if (g < 98304) {
        int e = g * 8; int piece = e >> 18; int rem = e & 262143;
        src = (piece == 0 ? Wq : piece == 1 ? Wk : Wv) + (size_t)l * 262144 + rem;
        dst = WQKVb + (size_t)l * 786432 + e;
    } else if (g < 131072) {
        int e = (g - 98304) * 8;
        src = Wo + (size_t)l * 262144 + e; dst = Wob + (size_t)l * 262144 + e;
    } else if (g < 262144) {
        int e = (g - 131072) * 8;
        src = W1 + (size_t)l * 1048576 + e; dst = W1b + (size_t)l * 1048576 + e;
    } else if (g < 393216) {
        int e = (g - 262144) * 8;
        src = W2 + (size_t)l * 1048576 + e; dst = W2b + (size_t)l * 1048576 + e;
    } else {
        int e = (g - 393216) * 8;             // 48 x 512 rel table
        int row = e >> 9, cc = e & 511;
        dst = relb + (size_t)l * 24576 + e;
        if (row < BUCKETS + 1) src = rel + ((size_t)l * (BUCKETS + 1) + row) * 512 + cc;
        else { src = nullptr; zero = true; }
    }
    uint4 o;
    if (zero) { o.x = o.y = o.z = o.w = 0u; }
    else {
        float4 x = *(const float4*)src, y = *(const float4*)(src + 4);
        o.x = (unsigned)f2bf(x.x) | ((unsigned)f2bf(x.y) << 16);
        o.y = (unsigned)f2bf(x.z) | ((unsigned)f2bf(x.w) << 16);
        o.z = (unsigned)f2bf(y.x) | ((unsigned)f2bf(y.y) << 16);
        o.w = (unsigned)f2bf(y.z) | ((unsigned)f2bf(y.w) << 16);
    }
    *(uint4*)dst = o;
    if (g < 3 * D) {
        int piece = g >> 9, r2 = g & 511;
        bqkv[l * 1536 + g] = (piece == 0 ? bq : piece == 1 ? bk : bv)[l * 512 + r2];
    }
}

// ---------------------------------------------------------------------------
// bf16 MFMA GEMM (m97 structure): 128x128 tile, BK=32, 4 waves, XOR-swizzled.
// VTOUT: columns >= 1024 (the V block of the fused QKV output) additionally
// write transposed VT[bh][d][ki] (bit-identical to the old vtrans pass).
// ---------------------------------------------------------------------------
template <bool RELU, bool OUTBF16, bool VTOUT>
__global__ __launch_bounds__(256) void mgemm_kernel(
    const unsigned short* __restrict__ A,
    const unsigned short* __restrict__ W,
    const float* __restrict__ bias,
    void* __restrict__ Cv,
    unsigned short* __restrict__ vt,
    int N, int M, int K)
{
    __shared__ short smA[2][128 * 32];
    __shared__ short smB[2][128 * 32];
    int tid = threadIdx.x;
    int bn = blockIdx.y * 128;
    int bm = blockIdx.x * 128;
    const unsigned short* Ab = A + (size_t)bn * K;
    const unsigned short* Wb = W + (size_t)bm * K;

    f32x4 acc[4][4];
#pragma unroll
    for (int i = 0; i < 4; i++)
#pragma unroll
        for (int j = 0; j < 4; j++) acc[i][j] = (f32x4){0.f, 0.f, 0.f, 0.f};

    const int c0 = tid, c1 = tid + 256;
    const int r0 = c0 >> 2, p0 = c0 & 3, l0 = p0 ^ ((r0 >> 1) & 3);
    const int r1 = c1 >> 2, p1 = c1 & 3, l1 = p1 ^ ((r1 >> 1) & 3);

    auto stage = [&](int buf, int k0) {
        stage16(Ab + (size_t)r0 * K + k0 + l0 * 8, &smA[buf][c0 * 8]);
        stage16(Ab + (size_t)r1 * K + k0 + l1 * 8, &smA[buf][c1 * 8]);
        stage16(Wb + (size_t)r0 * K + k0 + l0 * 8, &smB[buf][c0 * 8]);
        stage16(Wb + (size_t)r1 * K + k0 + l1 * 8, &smB[buf][c1 * 8]);
    };

    const int lane = tid & 63;
    const int wv = tid >> 6, wr = wv >> 1, wc = wv & 1;
    int aoff[4], boff[4];
#pragma unroll
    for (int i = 0; i < 4; i++) {
        int ra = wr * 64 + i * 16 + (lane & 15);
        int ca = (lane >> 4) ^ ((ra >> 1) & 3);
        aoff[i] = ra * 32 + ca * 8;
        int rb = wc * 64 + i * 16 + (lane & 15);
        int cb = (lane >> 4) ^ ((rb >> 1) & 3);
        boff[i] = rb * 32 + cb * 8;
    }

    stage(0, 0);
    const int nkt = K >> 5;
    for (int kt = 0; kt < nkt; ++kt) {
        __syncthreads();
        int cur = kt & 1;
        if (kt + 1 < nkt) stage(cur ^ 1, (kt + 1) << 5);
        const short* sa = smA[cur];
        const short* sb = smB[cur];
        bf16x8 af[4], bfr[4];
#pragma unroll
        for (int i = 0; i < 4; i++) af[i] = *(const bf16x8*)(sa + aoff[i]);
#pragma unroll
        for (int j = 0; j < 4; j++) bfr[j] = *(const bf16x8*)(sb + boff[j]);
#pragma unroll
        for (int i = 0; i < 4; i++)
#pragma unroll
            for (int j = 0; j < 4; j++)
                acc[i][j] = __builtin_amdgcn_mfma_f32_16x16x32_bf16(af[i], bfr[j], acc[i][j], 0, 0, 0);
    }

#pragma unroll
    for (int j = 0; j < 4; j++) {
        int col = bm + wc * 64 + j * 16 + (lane & 15);
        float bval = bias[col];
#pragma unroll
        for (int i = 0; i < 4; i++) {
            f32x4 v = acc[i][j];
            int row0 = bn + wr * 64 + i * 16 + (lane >> 4) * 4;
            unsigned short ob[4];
#pragma unroll
            for (int r = 0; r < 4; r++) {
                float val = v[r] + bval;
                if (RELU) val = fmaxf(val, 0.f);
                unsigned short bfv = f2bf(val);
                ob[r] = bfv;
                if (OUTBF16) ((unsigned short*)Cv)[(size_t)(row0 + r) * M + col] = bfv;
                else         ((float*)Cv)[(size_t)(row0 + r) * M + col] = val;
            }
            if (VTOUT && col >= 1024) {
                int d = col - 1024;                 // 0..511
                int b = row0 >> 8, ki = row0 & (T - 1);
                uint2 pk;
                pk.x = (unsigned)ob[0] | ((unsigned)ob[1] << 16);
                pk.y = (unsigned)ob[2] | ((unsigned)ob[3] << 16);
                *(uint2*)(vt + ((size_t)(b * H + (d >> 6)) * 64 + (d & 63)) * 256 + ki) = pk;
            }
        }
    }
}

// ---------------------------------------------------------------------------
// split-K bf16 MFMA GEMM: grid (M/128, N/128, S). P[s][n][m] partials.
// ---------------------------------------------------------------------------
__global__ __launch_bounds__(256) void mgemm_splitk_kernel(
    const unsigned short* __restrict__ A,
    const unsigned short* __restrict__ W,
    float* __restrict__ P,
    int N, int M, int K, int Ksub)
{
    __shared__ short smA[2][128 * 32];
    __shared__ short smB[2][128 * 32];
    int tid = threadIdx.x;
    int s = blockIdx.z;
    int bn = blockIdx.y * 128;
    int bm = blockIdx.x * 128;
    const unsigned short* Ab = A + (size_t)bn * K + s * Ksub;
    const unsigned short* Wb = W + (size_t)bm * K + s * Ksub;

    f32x4 acc[4][4];
#pragma unroll
    for (int i = 0; i < 4; i++)
#pragma unroll
        for (int j = 0; j < 4; j++) acc[i][j] = (f32x4){0.f, 0.f, 0.f, 0.f};

    const int c0 = tid, c1 = tid + 256;
    const int r0 = c0 >> 2, p0 = c0 & 3, l0 = p0 ^ ((r0 >> 1) & 3);
    const int r1 = c1 >> 2, p1 = c1 & 3, l1 = p1 ^ ((r1 >> 1) & 3);

    auto stage = [&](int buf, int k0) {
        stage16(Ab + (size_t)r0 * K + k0 + l0 * 8, &smA[buf][c0 * 8]);
        stage16(Ab + (size_t)r1 * K + k0 + l1 * 8, &smA[buf][c1 * 8]);
        stage16(Wb + (size_t)r0 * K + k0 + l0 * 8, &smB[buf][c0 * 8]);
        stage16(Wb + (size_t)r1 * K + k0 + l1 * 8, &smB[buf][c1 * 8]);
    };

    const int lane = tid & 63;
    const int wv = tid >> 6, wr = wv >> 1, wc = wv & 1;
    int aoff[4], boff[4];
#pragma unroll
    for (int i = 0; i < 4; i++) {
        int ra = wr * 64 + i * 16 + (lane & 15);
        int ca = (lane >> 4) ^ ((ra >> 1) & 3);
        aoff[i] = ra * 32 + ca * 8;
        int rb = wc * 64 + i * 16 + (lane & 15);
        int cb = (lane >> 4) ^ ((rb >> 1) & 3);
        boff[i] = rb * 32 + cb * 8;
    }

    stage(0, 0);
    const int nkt = Ksub >> 5;
    for (int kt = 0; kt < nkt; ++kt) {
        __syncthreads();
        int cur = kt & 1;
        if (kt + 1 < nkt) stage(cur ^ 1, (kt + 1) << 5);
        const short* sa = smA[cur];
        const short* sb = smB[cur];
        bf16x8 af[4], bfr[4];
#pragma unroll
        for (int i = 0; i < 4; i++) af[i] = *(const bf16x8*)(sa + aoff[i]);
#pragma unroll
        for (int j = 0; j < 4; j++) bfr[j] = *(const bf16x8*)(sb + boff[j]);
#pragma unroll
        for (int i = 0; i < 4; i++)
#pragma unroll
            for (int j = 0; j < 4; j++)
                acc[i][j] = __builtin_amdgcn_mfma_f32_16x16x32_bf16(af[i], bfr[j], acc[i][j], 0, 0, 0);
    }

#pragma unroll
    for (int j = 0; j < 4; j++) {
        int col = bm + wc * 64 + j * 16 + (lane & 15);
#pragma unroll
        for (int i = 0; i < 4; i++) {
            f32x4 v = acc[i][j];
#pragma unroll
            for (int r = 0; r < 4; r++) {
                int row = bn + wr * 64 + i * 16 + (lane >> 4) * 4 + r;
                P[((size_t)s * NT + row) * M + col] = v[r];
            }
        }
    }
}

// ---------------------------------------------------------------------------
// Fused MFMA attention (round-4/5 proven version)
// ---------------------------------------------------------------------------
__global__ __launch_bounds__(256) void fattn_kernel(
    const unsigned short* __restrict__ qkv,
    const unsigned short* __restrict__ vt,
    const unsigned short* __restrict__ relb,
    const float* __restrict__ uvec,
    const float* __restrict__ vvec,
    const int* __restrict__ dist,
    const int* __restrict__ lengths,
    unsigned short* __restrict__ ctx)
{
    __shared__ unsigned short Ps[4][16][256];
    __shared__ float Qrel[4][16][49];

    int bh = blockIdx.x, b = bh >> 3, h = bh & 7;
    int qi0 = blockIdx.y * 64;
    int tid = threadIdx.x, w = tid >> 6, lane = tid & 63;
    int l15 = lane & 15, g = lane >> 4;
    int qr = qi0 + w * 16;

    const unsigned short* qbase = qkv + (size_t)(b * T + qr + l15) * QKVLD + h * 64 + g * 8;
    bf16x8 qa0 = *(const bf16x8*)(qbase);
    bf16x8 qa1 = *(const bf16x8*)(qbase + 32);

    bf16x8 qu0, qu1;
    {
        const float* up = uvec + h * 64 + g * 8;
        float ua0[8], ua1[8];
        *(float4*)&ua0[0] = *(const float4*)(up);
        *(float4*)&ua0[4] = *(const float4*)(up + 4);
        *(float4*)&ua1[0] = *(const float4*)(up + 32);
        *(float4*)&ua1[4] = *(const float4*)(up + 36);
#pragma unroll
        for (int e = 0; e < 8; e++) {
            qu0[e] = (short)f2bf(0.125f * bf2f((unsigned short)qa0[e]) + ua0[e]);
            qu1[e] = (short)f2bf(0.125f * bf2f((unsigned short)qa1[e]) + ua1[e]);
        }
    }

    {
        const float* vp = vvec + h * 64 + g * 8;
        float va0[8], va1[8];
        *(float4*)&va0[0] = *(const float4*)(vp);
        *(float4*)&va0[4] = *(const float4*)(vp + 4);
        *(float4*)&va1[0] = *(const float4*)(vp + 32);
        *(float4*)&va1[4] = *(const float4*)(vp + 36);
        bf16x8 qh0, qh1;
#pragma unroll
        for (int e = 0; e < 8; e++) {
            qh0[e] = (short)f2bf(0.125f * bf2f((unsigned short)qa0[e]) + va0[e]);
            qh1[e] = (short)f2bf(0.125f * bf2f((unsigned short)qa1[e]) + va1[e]);
        }
        f32x4 qacc[3];
#pragma unroll
        for (int j = 0; j < 3; j++) qacc[j] = (f32x4){0.f, 0.f, 0.f, 0.f};
#pragma unroll
        for (int j = 0; j < 3; j++) {
            const unsigned short* rp = relb + (size_t)(j * 16 + l15) * 512 + h * 64 + g * 8;
            bf16x8 rr0 = *(const bf16x8*)(rp);
            bf16x8 rr1 = *(const bf16x8*)(rp + 32);
            qacc[j] = __builtin_amdgcn_mfma_f32_16x16x32_bf16(qh0, rr0, qacc[j], 0, 0, 0);
            qacc[j] = __builtin_amdgcn_mfma_f32_16x16x32_bf16(qh1, rr1, qacc[j], 0, 0, 0);
        }
#pragma unroll
        for (int j = 0; j < 3; j++)
#pragma unroll
            for (int r = 0; r < 4; r++)
                Qrel[w][g * 4 + r][j * 16 + l15] = qacc[j][r];
    }

    f32x4 acc[16];
#pragma unroll
    for (int j = 0; j < 16; j++) acc[j] = (f32x4){0.f, 0.f, 0.f, 0.f};
    const unsigned short* kbase = qkv + (size_t)(b * T) * QKVLD + 512 + h * 64 + g * 8;
#pragma unroll
    for (int j = 0; j < 16; j++) {
        const unsigned short* kp = kbase + (size_t)(j * 16 + l15) * QKVLD;
        bf16x8 k0 = *(const bf16x8*)(kp);
        bf16x8 k1 = *(const bf16x8*)(kp + 32);
        acc[j] = __builtin_amdgcn_mfma_f32_16x16x32_bf16(qu0, k0, acc[j], 0, 0, 0);
        acc[j] = __builtin_amdgcn_mfma_f32_16x16x32_bf16(qu1, k1, acc[j], 0, 0, 0);
    }

    int len = lengths[b];
    float rinv[4];
    const int* db = dist + (size_t)b * T * T;
#pragma unroll
    for (int r = 0; r < 4; r++) {
        int rowloc = g * 4 + r;
        int qrow = qr + rowloc;
        const int* dpr = db + (size_t)qrow * T;
        float m = -3.0e38f;
#pragma unroll
        for (int j = 0; j < 16; j++) {
            int ki = j * 16 + l15;
            int dv = dpr[ki];
            float s = acc[j][r] + Qrel[w][rowloc][dv];
            s = (ki < len) ? s : -1.0e30f;
            acc[j][r] = s;
            m = fmaxf(m, s);
        }
#pragma unroll
        for (int o = 8; o; o >>= 1) m = fmaxf(m, __shfl_xor(m, o));
        float sum = 0.f;
#pragma unroll
        for (int j = 0; j < 16; j++) {
            int ki = j * 16 + l15;
            float p = __expf(acc[j][r] - m);
            sum += p;
            int cph = ((ki >> 3) ^ (rowloc & 7));
            Ps[w][rowloc][cph * 8 + (ki & 7)] = f2bf(p);
        }
#pragma unroll
        for (int o = 8; o; o >>= 1) sum += __shfl_xor(sum, o);
        rinv[r] = 1.0f / sum;
    }

    f32x4 oacc[4];
#pragma unroll
    for (int j = 0; j < 4; j++) oacc[j] = (f32x4){0.f, 0.f, 0.f, 0.f};
    const unsigned short* vtb = vt + (size_t)bh * 64 * 256;
#pragma unroll
    for (int ks = 0; ks < 8; ks++) {
        int c = ks * 4 + g;
        int cph = c ^ (l15 & 7);
        bf16x8 pa = *(const bf16x8*)&Ps[w][l15][cph * 8];
#pragma unroll
        for (int j2 = 0; j2 < 4; j2++) {
            bf16x8 vb = *(const bf16x8*)(vtb + (size_t)(j2 * 16 + l15) * 256 + c * 8);
            oacc[j2] = __builtin_amdgcn_mfma_f32_16x16x32_bf16(pa, vb, oacc[j2], 0, 0, 0);
        }
    }

#pragma unroll
    for (int j2 = 0; j2 < 4; j2++) {
#pragma unroll
        for (int r = 0; r < 4; r++) {
            int qrow = qr + g * 4 + r;
            int dcol = j2 * 16 + l15;
            ctx[(size_t)(b * T + qrow) * D + h * 64 + dcol] = f2bf(oacc[j2][r] * rinv[r]);
        }
    }
}

// ---------------------------------------------------------------------------
extern "C" void kernel_launch(void* const* d_in, const int* in_sizes, int n_in,
                              void* d_out, int out_size, void* d_ws, size_t ws_size,
                              hipStream_t stream)
{
    const float* src     = (const float*)d_in[0];
    const int*   lengths = (const int*)d_in[1];
    const int*   dist    = (const int*)d_in[2];
    const float* u       = (const float*)d_in[3];
    const float* v       = (const float*)d_in[4];
    const float* ln1_g   = (const float*)d_in[5];
    const float* ln1_b   = (const float*)d_in[6];
    const float* Wq      = (const float*)d_in[7];
    const float* Wk      = (const float*)d_in[8];
    const float* Wv      = (const float*)d_in[9];
    const float* Wo      = (const float*)d_in[10];
    const float* bq      = (const float*)d_in[11];
    const float* bk      = (const float*)d_in[12];
    const float* bv      = (const float*)d_in[13];
    const float* bo      = (const float*)d_in[14];
    const float* rel     = (const float*)d_in[15];
    const float* fg      = (const float*)d_in[16];
    const float* fb      = (const float*)d_in[17];
    const float* W1      = (const float*)d_in[18];
    const float* b1      = (const float*)d_in[19];
    const float* W2      = (const float*)d_in[20];
    const float* b2      = (const float*)d_in[21];
    const float* flg     = (const float*)d_in[22];
    const float* flb     = (const float*)d_in[23];

    float* ws = (float*)d_ws;
    float*          X     = ws;                                   // 1048576 f
    unsigned short* QKVb  = (unsigned short*)(ws + 1048576);      // 3145728 bf16
    unsigned short* Hb    = (unsigned short*)(ws + 2621440);      // 1048576 bf16
    unsigned short* CTX   = (unsigned short*)(ws + 3145728);      // 1048576 bf16
    unsigned short* FF1   = (unsigned short*)(ws + 3670016);      // 4194304 bf16
    unsigned short* VT    = (unsigned short*)(ws + 5767168);      // 1048576 bf16
    float*          Pbuf  = ws + 6291456;                         // 4x2048x512 f32
    unsigned short* WQKVb = (unsigned short*)(ws + 10485760);     // 4x786432 bf16
    unsigned short* Wob   = (unsigned short*)(ws + 12058624);     // 4x262144 bf16
    unsigned short* W1b   = (unsigned short*)(ws + 12582912);     // 4x1048576 bf16
    unsigned short* W2b   = (unsigned short*)(ws + 14680064);     // 4x1048576 bf16
    unsigned short* RELb  = (unsigned short*)(ws + 16777216);     // 4x24576 bf16
    float*          bqkv  = ws + 16826368;                        // 4x1536 f

    convert_all_kernel<<<dim3(1548, L), 256, 0, stream>>>(
        Wq, Wk, Wv, Wo, W1, W2, bq, bk, bv, rel,
        WQKVb, Wob, W1b, W2b, RELb, bqkv);

    embed_ln_kernel<<<NT, 256, 0, stream>>>(src, X, Hb, ln1_g, ln1_b);

    for (int l = 0; l < L; l++) {
        const unsigned short* wqkv = WQKVb + (size_t)l * 786432;
        const unsigned short* wob  = Wob   + (size_t)l * 262144;
        const unsigned short* w1b  = W1b   + (size_t)l * 1048576;
        const unsigned short* w2b  = W2b   + (size_t)l * 1048576;
        const unsigned short* relb = RELb  + (size_t)l * 24576;
        const float*          bql  = bqkv  + (size_t)l * 1536;

        if (l > 0)
            lnr_kernel<<<NT, 256, 0, stream>>>(X, Pbuf, b2 + (size_t)(l - 1) * D,
                                               Hb, ln1_g + l * D, ln1_b + l * D);

        // fused QKV GEMM, V columns also written transposed into VT
        mgemm_kernel<false, true, true><<<dim3(12, 16), 256, 0, stream>>>(
            Hb, wqkv, bql, QKVb, VT, NT, QKVLD, D);

        fattn_kernel<<<dim3(B * H, T / 64), 256, 0, stream>>>(
            QKVb, VT, relb, u, v, dist, lengths, CTX);

        mgemm_splitk_kernel<<<dim3(4, 16, 4), 256, 0, stream>>>(
            CTX, wob, Pbuf, NT, D, D, D / 4);

        lnr_kernel<<<NT, 256, 0, stream>>>(X, Pbuf, bo + (size_t)l * D,
                                           Hb, fg + l * D, fb + l * D);

        mgemm_kernel<true, true, false><<<dim3(16, 16), 256, 0, stream>>>(
            Hb, w1b, b1 + (size_t)l * DFF, FF1, nullptr, NT, DFF, D);

        mgemm_splitk_kernel<<<dim3(4, 16, 4), 256, 0, stream>>>(
            FF1, w2b, Pbuf, NT, D, DFF, DFF / 4);
    }

    final_lnr_kernel<<<NT, 256, 0, stream>>>(X, Pbuf, b2 + (size_t)(L - 1) * D,
                                             (float*)d_out, flg, flb);
}